// Round 23
// baseline (244.905 us; speedup 1.0000x reference)
//
#include <hip/hip_runtime.h>
#include <hip/hip_bf16.h>

#define DI 768
#define SS 2048
#define QK_ELEMS ((size_t)16384 * 768)

typedef float f32x4 __attribute__((ext_vector_type(4)));
typedef short s16x8 __attribute__((ext_vector_type(8)));
typedef short s16x4 __attribute__((ext_vector_type(4)));

static __device__ __forceinline__ unsigned short f2bf(float f) {
    union { float f; unsigned int u; } a; a.f = f;
    unsigned int r = (a.u + 0x7FFFu + ((a.u >> 16) & 1u)) >> 16; // RNE
    return (unsigned short)r;
}

#define GLOAD_LDS16(SRC, DST) \
    __builtin_amdgcn_global_load_lds((const __attribute__((address_space(1))) unsigned int*)(SRC), \
                                     (__attribute__((address_space(3))) unsigned int*)(DST), 16, 0, 0)

// ---------------- x -> bf16 (stashed in d_out; attn overwrites it later) -----
__global__ __launch_bounds__(256) void conv_kernel(
    const float* __restrict__ x, unsigned short* __restrict__ xb)
{
    const size_t i = ((size_t)blockIdx.x * 256 + threadIdx.x) * 8;
    float4 a = *(const float4*)(x + i);
    float4 c = *(const float4*)(x + i + 4);
    ushort4 u0, u1;
    u0.x = f2bf(a.x); u0.y = f2bf(a.y); u0.z = f2bf(a.z); u0.w = f2bf(a.w);
    u1.x = f2bf(c.x); u1.y = f2bf(c.y); u1.z = f2bf(c.z); u1.w = f2bf(c.w);
    *(ushort4*)(xb + i) = u0;
    *(ushort4*)(xb + i + 4) = u1;
}

// ---------------- weights -> bf16 TRANSPOSED: wtb[which][n][k] = w[k][n] -----
__global__ __launch_bounds__(256) void convw_kernel(
    const float* __restrict__ wq, const float* __restrict__ wk,
    const float* __restrict__ wv, unsigned short* __restrict__ wtb)
{
    __shared__ float tile[64][65];
    const int which = blockIdx.z;
    const float* w = (which == 0) ? wq : (which == 1) ? wk : wv;
    unsigned short* o = wtb + (size_t)which * DI * DI;
    const int k0 = blockIdx.x * 64, n0 = blockIdx.y * 64;
    const int tid = threadIdx.x;
    #pragma unroll
    for (int i = 0; i < 16; ++i) {
        int idx = tid + i * 256;
        int rr = idx >> 6, cc = idx & 63;
        tile[rr][cc] = w[(size_t)(k0 + rr) * DI + n0 + cc];
    }
    __syncthreads();
    #pragma unroll
    for (int i = 0; i < 16; ++i) {
        int idx = tid + i * 256;
        int rr = idx >> 6, cc = idx & 63;
        o[(size_t)(n0 + rr) * DI + k0 + cc] = f2bf(tile[cc][rr]);
    }
}

// ---------------- projection: 256x128 tile, BK=64, 2-DEEP counted-vmcnt ------
// 3 LDS buffers (144 KB); prologue stages tiles 0,1; iter kt waits vmcnt(6)
// (oldest 6 = tile kt's stages; tile kt+1 stays in flight - T4), computes from
// buf kt%3 while issuing tile kt+2. No vmcnt(0) drain in the main loop.
// Q [q/32][d/8][q%32][8] pre-scaled; K [s/64][d/8][s%64][8]; V frag-packed.
__global__ __launch_bounds__(512, 1) void proj_kernel(
    const unsigned short* __restrict__ xb, const unsigned short* __restrict__ wtb,
    unsigned short* __restrict__ ws)
{
    __shared__ unsigned short LA[3 * 16384];    // 96 KB: A bufs (256x64 each)
    __shared__ unsigned short LB[3 * 8192];     // 48 KB: B bufs (128x64 each)

    const int which = blockIdx.z;
    const unsigned short* wt = wtb + (size_t)which * DI * DI;  // [n][k] bf16
    const int n0 = blockIdx.x * 128;
    const int m0 = blockIdx.y * 256;
    const int tid = threadIdx.x;
    const int l = tid & 63, w = tid >> 6;
    const int wm = w >> 2, wn = w & 3;
    const int r = l & 15, g = l >> 4;

    const int scol = ((l & 7) ^ ((l >> 3) & 7)) * 8;  // pre-swizzled src col (shorts)
    const int srow = w * 16 + (l >> 3);               // staged row (i adds 8)

    f32x4 acc[8][2];
    #pragma unroll
    for (int i = 0; i < 8; ++i) {
        acc[i][0] = (f32x4){0.f, 0.f, 0.f, 0.f};
        acc[i][1] = (f32x4){0.f, 0.f, 0.f, 0.f};
    }

#define STAGE_A(KT, H) do { \
        const int b_ = (KT) % 3; \
        _Pragma("unroll") \
        for (int i_ = 0; i_ < 2; ++i_) \
            GLOAD_LDS16(xb + (size_t)(m0 + (H) * 128 + srow + i_ * 8) * DI + (KT) * 64 + scol, \
                        &LA[b_ * 16384 + (H) * 8192 + w * 1024 + i_ * 512]); \
    } while (0)
#define STAGE_B(KT) do { \
        const int b_ = (KT) % 3; \
        _Pragma("unroll") \
        for (int i_ = 0; i_ < 2; ++i_) \
            GLOAD_LDS16(wt + (size_t)(n0 + srow + i_ * 8) * DI + (KT) * 64 + scol, \
                        &LB[b_ * 8192 + w * 1024 + i_ * 512]); \
    } while (0)

    // prologue: stage tiles 0 and 1 (6 gl_lds per thread each)
    STAGE_A(0, 0); STAGE_A(0, 1); STAGE_B(0);
    STAGE_A(1, 0); STAGE_A(1, 1); STAGE_B(1);

    for (int kt = 0; kt < 12; ++kt) {
        if (kt == 11) asm volatile("s_waitcnt vmcnt(0)" ::: "memory");
        else          asm volatile("s_waitcnt vmcnt(6)" ::: "memory");
        __builtin_amdgcn_sched_barrier(0);
        __builtin_amdgcn_s_barrier();
        __builtin_amdgcn_sched_barrier(0);

        const unsigned short* Ab = &LA[(kt % 3) * 16384];
        const unsigned short* Bb = &LB[(kt % 3) * 8192];
        const bool pf = (kt + 2 < 12);

        #pragma unroll
        for (int q = 0; q < 4; ++q) {
            if (pf) {
                if (q == 0) STAGE_A(kt + 2, 0);
                else if (q == 1) STAGE_A(kt + 2, 1);
                else if (q == 2) STAGE_B(kt + 2);
            }
            const int kk = q >> 1, frh = q & 1;
            const int koff = (kk * 32 + g * 8) ^ ((r & 7) << 3);
            s16x8 af[4], bf[2];
            #pragma unroll
            for (int fr = 0; fr < 4; ++fr)
                af[fr] = *(const s16x8*)&Ab[(wm * 128 + frh * 64 + fr * 16 + r) * 64 + koff];
            #pragma unroll
            for (int cf = 0; cf < 2; ++cf)
                bf[cf] = *(const s16x8*)&Bb[(wn * 32 + cf * 16 + r) * 64 + koff];
            __builtin_amdgcn_s_setprio(1);
            #pragma unroll
            for (int fr = 0; fr < 4; ++fr)
                #pragma unroll
                for (int cf = 0; cf < 2; ++cf)
                    acc[frh * 4 + fr][cf] =
                        __builtin_amdgcn_mfma_f32_16x16x32_bf16(af[fr], bf[cf], acc[frh * 4 + fr][cf], 0, 0, 0);
            __builtin_amdgcn_s_setprio(0);
        }
    }

    if (which == 0) {
        const float scale = 0.03608439182435161f;   // 1/sqrt(768)
        unsigned short* O = ws;                     // Q [q/32][d/8][q%32][8]
        #pragma unroll
        for (int fr = 0; fr < 8; ++fr)
            #pragma unroll
            for (int cf = 0; cf < 2; ++cf) {
                int row = m0 + wm * 128 + fr * 16 + g * 4;
                int col = n0 + wn * 32 + cf * 16 + r;
                #pragma unroll
                for (int jj = 0; jj < 4; ++jj) {
                    int q = row + jj;
                    O[((size_t)(q >> 5) * 96 + (col >> 3)) * 256 + (q & 31) * 8 + (col & 7)]
                        = f2bf(acc[fr][cf][jj] * scale);
                }
            }
    } else if (which == 1) {
        unsigned short* O = ws + QK_ELEMS;          // K [s/64][d/8][s%64][8]
        #pragma unroll
        for (int fr = 0; fr < 8; ++fr)
            #pragma unroll
            for (int cf = 0; cf < 2; ++cf) {
                int row = m0 + wm * 128 + fr * 16 + g * 4;
                int col = n0 + wn * 32 + cf * 16 + r;
                #pragma unroll
                for (int jj = 0; jj < 4; ++jj) {
                    int s = row + jj;
                    O[((size_t)(s >> 6) * 96 + (col >> 3)) * 512 + (s & 63) * 8 + (col & 7)]
                        = f2bf(acc[fr][cf][jj]);
                }
            }
    } else {
        unsigned short* O = ws + 2 * QK_ELEMS;      // Vf fragment-packed
        #pragma unroll
        for (int fr = 0; fr < 8; ++fr)
            #pragma unroll
            for (int cf = 0; cf < 2; ++cf) {
                int row = m0 + wm * 128 + fr * 16 + g * 4;   // = b*2048 + s
                int bb = row >> 11;
                int st = (row & 2047) >> 4;
                int et = ((n0 + wn * 32) >> 4) + cf;
                ushort4 pk;
                pk.x = f2bf(acc[fr][cf][0]); pk.y = f2bf(acc[fr][cf][1]);
                pk.z = f2bf(acc[fr][cf][2]); pk.w = f2bf(acc[fr][cf][3]);
                *(ushort4*)&O[(((size_t)bb * 128 + st) * 48 + et) * 256 + l * 4] = pk;
            }
    }
#undef STAGE_A
#undef STAGE_B
}

// ---------------- fused causal attention (R20-exact: best measured, 130.7us) -
__global__ __launch_bounds__(512, 1) void attn_kernel(
    const unsigned short* __restrict__ ws, float* __restrict__ out)
{
    __shared__ unsigned short Ks[96 * 512];     // 96 KB: [96 dg][64 s][8]
    __shared__ unsigned short Qs[96 * 256];     // 48 KB: [96 dg][32 q][8]
    __shared__ unsigned short P_lds[2048];      // [qsel][slice][16q][16k]
    __shared__ float redm[128];                 // [qsel][slice][16q] lp partials

    const int id = blockIdx.x;
    const int b = id & 7;                  // one batch per XCD
    const int a = id >> 3;                 // 0..31
    const int tid = threadIdx.x;
    const int wid = tid >> 6, lane = tid & 63;
    const int qsel = wid >> 2;             // q-tile of the pair (QK role)
    const int wv = wid & 3;                // k-slice owner (QK role)
    const int r = lane & 15, g = lane >> 4;
    const int et0 = wid * 6;               // PV role: e-eighth base (e0 = wid*96)
    const int rw = wv * 16 + r;

    const unsigned short* Qb = ws + (size_t)b * SS * DI;                // d-chunk-major
    const unsigned short* Kb = ws + QK_ELEMS + (size_t)b * SS * DI;     // d-chunk-major
    const unsigned short* Vf = ws + 2 * QK_ELEMS + (size_t)b * 128 * 48 * 256;
    float* Ob = out + (size_t)b * SS * DI;
    const char* KsB = (const char*)Ks;
    const char* QsB = (const char*)Qs;
    const int kfb = g * 1024 + rw * 16;    // per-lane K fragment base (bytes)
    const int qfb = g * 512 + (qsel * 16 + r) * 16;  // per-lane Q fragment base

#define STAGEK(KT) do { \
        const size_t sbase_ = (size_t)(KT) * 64 * DI; \
        _Pragma("unroll") \
        for (int i_ = 0; i_ < 12; ++i_) { \
            const int idx_ = wid * 12 + i_; \
            GLOAD_LDS16(Kb + sbase_ + idx_ * 512 + lane * 8, &Ks[idx_ * 512]); \
        } \
    } while (0)

#define RAWBAR() do { \
        asm volatile("s_waitcnt lgkmcnt(0)" ::: "memory"); \
        __builtin_amdgcn_sched_barrier(0); \
        __builtin_amdgcn_s_barrier(); \
        __builtin_amdgcn_sched_barrier(0); \
    } while (0)

    for (int pp = 0; pp < 2; ++pp) {
        const int jbase = pp ? (126 - 2 * a) : (2 * a);
        const int q0 = (jbase + qsel) * 16;        // own S-tile q-rows
        const int nt0 = (jbase * 16 + 79) >> 6;    // q-tile 0 activity
        const int ntmax = ((jbase + 1) * 16 + 79) >> 6;
        const int nt_own = qsel ? ntmax : nt0;

        // prologue: stage Q pair (48KB linear) + K tile 0
        {
            const size_t qsb = (size_t)jbase * 16 * DI;
            #pragma unroll
            for (int i_ = 0; i_ < 6; ++i_) {
                const int idx_ = wid * 6 + i_;
                GLOAD_LDS16(Qb + qsb + idx_ * 512 + lane * 8, &Qs[idx_ * 512]);
            }
        }
        STAGEK(0);

        f32x4 acc[2][6];
        #pragma unroll
        for (int qs = 0; qs < 2; ++qs)
            #pragma unroll
            for (int cf = 0; cf < 6; ++cf) acc[qs][cf] = (f32x4){0.f, 0.f, 0.f, 0.f};
        float lp = 0.f;

        for (int kt = 0; kt < ntmax; ++kt) {
            const int k0 = kt * 64;
            const bool act0 = kt < nt0;
            const bool act_own = kt < nt_own;
            __syncthreads();                        // A: K(kt)+Q staged (vmcnt drain)

            // V prefetch (shared by both q-tiles; consumed in PV)
            s16x4 va[4][6];
            const size_t vbase = ((size_t)(k0 >> 4) * 48 + et0) * 256 + lane * 4;
            #pragma unroll
            for (int ks = 0; ks < 4; ++ks)
                #pragma unroll
                for (int cf = 0; cf < 6; ++cf)
                    va[ks][cf] = *(const s16x4*)(Vf + vbase + (size_t)ks * 48 * 256 + cf * 256);

            if (act_own) {
                f32x4 sa = {0,0,0,0}, sb = {0,0,0,0};
                __builtin_amdgcn_s_setprio(1);
                #pragma unroll
                for (int t = 0; t < 24; t += 2) {
                    s16x8 ka  = *(const s16x8*)(KsB + kfb + t * 4096);
                    s16x8 kb2 = *(const s16x8*)(KsB + kfb + t * 4096 + 4096);
                    s16x8 qa  = *(const s16x8*)(QsB + qfb + t * 2048);
                    s16x8 qb2 = *(const s16x8*)(QsB + qfb + t * 2048 + 2048);
                    sa = __builtin_amdgcn_mfma_f32_16x16x32_bf16(ka,  qa,  sa, 0, 0, 0);
                    sb = __builtin_amdgcn_mfma_f32_16x16x32_bf16(kb2, qb2, sb, 0, 0, 0);
                }
                __builtin_amdgcn_s_setprio(0);
                f32x4 s;
                #pragma unroll
                for (int jj = 0; jj < 4; ++jj) s[jj] = sa[jj] + sb[jj];
                if (k0 + 64 > q0) {                 // boundary: causal mask
                    #pragma unroll
                    for (int jj = 0; jj < 4; ++jj)
                        if (k0 + 16 * wv + 4 * g + jj > q0 + r) s[jj] = -1e30f;
                }
                // fixed-reference softmax numerator: p = exp(s)
                s16x4 pw;
                #pragma unroll
                for (int jj = 0; jj < 4; ++jj) {
                    float p = __expf(s[jj]);
                    lp += p;
                    pw[jj] = (short)f2bf(p);
                }
                *(s16x4*)&P_lds[qsel * 1024 + wv * 256 + r * 16 + g * 4] = pw;
            }
            RAWBAR();                               // C: P ready, K consumed

            if (kt + 1 < ntmax) STAGEK(kt + 1);     // flies under PV into next A

            {
                s16x4 pa0[4], pa1[4];
                #pragma unroll
                for (int ks = 0; ks < 4; ++ks) {
                    pa0[ks] = *(const s16x4*)&P_lds[ks * 256 + r * 16 + g * 4];
                    pa1[ks] = *(const s16x4*)&P_lds[1024 + ks * 256 + r * 16 + g * 4];
                }
                __builtin_amdgcn_s_setprio(1);
                if (act0) {
                    #pragma unroll
                    for (int cf = 0; cf < 6; ++cf)
                        #pragma unroll
                        for (int ks = 0; ks < 4; ++ks)
                            acc[0][cf] = __builtin_amdgcn_mfma_f32_16x16x16bf16_1k(pa0[ks], va[ks][cf], acc[0][cf], 0, 0, 0);
                }
                #pragma unroll
                for (int cf = 0; cf < 6; ++cf)
                    #pragma unroll
                    for (int ks = 0; ks < 4; ++ks)
                        acc[1][cf] = __builtin_amdgcn_mfma_f32_16x16x16bf16_1k(pa1[ks], va[ks][cf], acc[1][cf], 0, 0, 0);
                __builtin_amdgcn_s_setprio(0);
            }
        }
        // epilogue: combine per-slice lp, normalize, store both q-tiles
        lp += __shfl_xor(lp, 16);
        lp += __shfl_xor(lp, 32);
        if (lane < 16) redm[qsel * 64 + wv * 16 + lane] = lp;
        __syncthreads();
        const float lt0 = redm[r] + redm[16 + r] + redm[32 + r] + redm[48 + r];
        const float lt1 = redm[64 + r] + redm[80 + r] + redm[96 + r] + redm[112 + r];
        const float li0 = 1.0f / lt0, li1 = 1.0f / lt1;
        float lv0[4], lv1[4];
        #pragma unroll
        for (int jj = 0; jj < 4; ++jj) {
            lv0[jj] = __shfl(li0, 4 * g + jj);
            lv1[jj] = __shfl(li1, 4 * g + jj);
        }
        #pragma unroll
        for (int cf = 0; cf < 6; ++cf)
            #pragma unroll
            for (int jj = 0; jj < 4; ++jj) {
                Ob[(size_t)(jbase * 16 + 4 * g + jj) * DI + wid * 96 + cf * 16 + r] = acc[0][cf][jj] * lv0[jj];
                Ob[(size_t)((jbase + 1) * 16 + 4 * g + jj) * DI + wid * 96 + cf * 16 + r] = acc[1][cf][jj] * lv1[jj];
            }
        __syncthreads();                            // Qs/P_lds/redm safe for next pass
    }
#undef STAGEK
#undef RAWBAR
}

extern "C" void kernel_launch(void* const* d_in, const int* in_sizes, int n_in,
                              void* d_out, int out_size, void* d_ws, size_t ws_size,
                              hipStream_t stream) {
    const float* x  = (const float*)d_in[0];
    const float* wq = (const float*)d_in[1];
    const float* wk = (const float*)d_in[2];
    const float* wv = (const float*)d_in[3];
    unsigned short* ws = (unsigned short*)d_ws;
    float* out = (float*)d_out;
    unsigned short* xb  = (unsigned short*)d_out;            // bf16(x), 25.2 MB
    unsigned short* wtb = (unsigned short*)d_out + QK_ELEMS; // bf16 W^T, 3.5 MB

    conv_kernel<<<(int)(QK_ELEMS / (256 * 8)), 256, 0, stream>>>(x, xb);
    convw_kernel<<<dim3(12, 12, 3), 256, 0, stream>>>(wq, wk, wv, wtb);
    proj_kernel<<<dim3(6, 64, 3), 512, 0, stream>>>(xb, wtb, ws);
    attn_kernel<<<256, 512, 0, stream>>>(ws, out);
}

// Round 24
// 236.647 us; speedup vs baseline: 1.0349x; 1.0349x over previous
//
#include <hip/hip_runtime.h>
#include <hip/hip_bf16.h>

#define DI 768
#define SS 2048
#define QK_ELEMS ((size_t)16384 * 768)

typedef float f32x4 __attribute__((ext_vector_type(4)));
typedef short s16x8 __attribute__((ext_vector_type(8)));
typedef short s16x4 __attribute__((ext_vector_type(4)));

static __device__ __forceinline__ unsigned short f2bf(float f) {
    union { float f; unsigned int u; } a; a.f = f;
    unsigned int r = (a.u + 0x7FFFu + ((a.u >> 16) & 1u)) >> 16; // RNE
    return (unsigned short)r;
}

#define GLOAD_LDS16(SRC, DST) \
    __builtin_amdgcn_global_load_lds((const __attribute__((address_space(1))) unsigned int*)(SRC), \
                                     (__attribute__((address_space(3))) unsigned int*)(DST), 16, 0, 0)

// ------- prep: x -> bf16 (xb) AND weights -> bf16 transposed (wtb), one kernel
__global__ __launch_bounds__(256) void prep_kernel(
    const float* __restrict__ x, const float* __restrict__ wq,
    const float* __restrict__ wk, const float* __restrict__ wv,
    unsigned short* __restrict__ xb, unsigned short* __restrict__ wtb)
{
    __shared__ float tile[64][65];
    const int bid = blockIdx.x;
    const int tid = threadIdx.x;
    if (bid < 6144) {                       // conv part: 6144*2048 = QK_ELEMS
        const size_t i = ((size_t)bid * 256 + tid) * 8;
        float4 a = *(const float4*)(x + i);
        float4 c = *(const float4*)(x + i + 4);
        ushort4 u0, u1;
        u0.x = f2bf(a.x); u0.y = f2bf(a.y); u0.z = f2bf(a.z); u0.w = f2bf(a.w);
        u1.x = f2bf(c.x); u1.y = f2bf(c.y); u1.z = f2bf(c.z); u1.w = f2bf(c.w);
        *(ushort4*)(xb + i) = u0;
        *(ushort4*)(xb + i + 4) = u1;
    } else {                                // convw part: 432 blocks
        const int cid = bid - 6144;
        const int which = cid / 144, rem = cid % 144;
        const int k0 = (rem / 12) * 64, n0 = (rem % 12) * 64;
        const float* w = (which == 0) ? wq : (which == 1) ? wk : wv;
        unsigned short* o = wtb + (size_t)which * DI * DI;
        #pragma unroll
        for (int i = 0; i < 16; ++i) {
            int idx = tid + i * 256;
            int rr = idx >> 6, cc = idx & 63;
            tile[rr][cc] = w[(size_t)(k0 + rr) * DI + n0 + cc];
        }
        __syncthreads();
        #pragma unroll
        for (int i = 0; i < 16; ++i) {
            int idx = tid + i * 256;
            int rr = idx >> 6, cc = idx & 63;
            o[(size_t)(n0 + rr) * DI + k0 + cc] = f2bf(tile[cc][rr]);
        }
    }
}

// ---------------- projection: 256x128 tile, BK=64, 2-buffer (R20-exact) ------
// Q [q/32][d/8][q%32][8] pre-scaled; K [s/64][d/8][s%64][8]; V frag-packed.
__global__ __launch_bounds__(512, 1) void proj_kernel(
    const unsigned short* __restrict__ xb, const unsigned short* __restrict__ wtb,
    unsigned short* __restrict__ ws)
{
    __shared__ unsigned short L[2 * 16384 + 2 * 8192];  // 96 KB

    const int which = blockIdx.z;
    const unsigned short* wt = wtb + (size_t)which * DI * DI;  // [n][k] bf16
    const int n0 = blockIdx.x * 128;
    const int m0 = blockIdx.y * 256;
    const int tid = threadIdx.x;
    const int l = tid & 63, w = tid >> 6;
    const int wm = w >> 2, wn = w & 3;
    const int r = l & 15, g = l >> 4;

    const int scol = ((l & 7) ^ ((l >> 3) & 7)) * 8;  // pre-swizzled src col (shorts)
    const int srow = w * 16 + (l >> 3);               // staged row (i adds 8)

    f32x4 acc[8][2];
    #pragma unroll
    for (int i = 0; i < 8; ++i) {
        acc[i][0] = (f32x4){0.f, 0.f, 0.f, 0.f};
        acc[i][1] = (f32x4){0.f, 0.f, 0.f, 0.f};
    }

#define STAGE_A(KT, H) do { \
        const int b_ = (KT) & 1; \
        _Pragma("unroll") \
        for (int i_ = 0; i_ < 2; ++i_) \
            GLOAD_LDS16(xb + (size_t)(m0 + (H) * 128 + srow + i_ * 8) * DI + (KT) * 64 + scol, \
                        &L[b_ * 16384 + (H) * 8192 + w * 1024 + i_ * 512]); \
    } while (0)
#define STAGE_B(KT) do { \
        const int b_ = (KT) & 1; \
        _Pragma("unroll") \
        for (int i_ = 0; i_ < 2; ++i_) \
            GLOAD_LDS16(wt + (size_t)(n0 + srow + i_ * 8) * DI + (KT) * 64 + scol, \
                        &L[32768 + b_ * 8192 + w * 1024 + i_ * 512]); \
    } while (0)

    STAGE_A(0, 0); STAGE_A(0, 1); STAGE_B(0);   // prologue: K-tile 0

    for (int kt = 0; kt < 12; ++kt) {
        const int b = kt & 1;
        asm volatile("s_waitcnt vmcnt(0)" ::: "memory");
        __builtin_amdgcn_sched_barrier(0);
        __builtin_amdgcn_s_barrier();
        __builtin_amdgcn_sched_barrier(0);

        const unsigned short* Ab = &L[b * 16384];
        const unsigned short* Bb = &L[32768 + b * 8192];
        const bool pf = (kt + 1 < 12);

        #pragma unroll
        for (int q = 0; q < 4; ++q) {
            if (pf) {
                if (q == 0) STAGE_A(kt + 1, 0);
                else if (q == 1) STAGE_A(kt + 1, 1);
                else if (q == 2) STAGE_B(kt + 1);
            }
            const int kk = q >> 1, frh = q & 1;
            const int koff = (kk * 32 + g * 8) ^ ((r & 7) << 3);
            s16x8 af[4], bf[2];
            #pragma unroll
            for (int fr = 0; fr < 4; ++fr)
                af[fr] = *(const s16x8*)&Ab[(wm * 128 + frh * 64 + fr * 16 + r) * 64 + koff];
            #pragma unroll
            for (int cf = 0; cf < 2; ++cf)
                bf[cf] = *(const s16x8*)&Bb[(wn * 32 + cf * 16 + r) * 64 + koff];
            __builtin_amdgcn_s_setprio(1);
            #pragma unroll
            for (int fr = 0; fr < 4; ++fr)
                #pragma unroll
                for (int cf = 0; cf < 2; ++cf)
                    acc[frh * 4 + fr][cf] =
                        __builtin_amdgcn_mfma_f32_16x16x32_bf16(af[fr], bf[cf], acc[frh * 4 + fr][cf], 0, 0, 0);
            __builtin_amdgcn_s_setprio(0);
        }
    }

    if (which == 0) {
        const float scale = 0.03608439182435161f;   // 1/sqrt(768)
        unsigned short* O = ws;                     // Q [q/32][d/8][q%32][8]
        #pragma unroll
        for (int fr = 0; fr < 8; ++fr)
            #pragma unroll
            for (int cf = 0; cf < 2; ++cf) {
                int row = m0 + wm * 128 + fr * 16 + g * 4;
                int col = n0 + wn * 32 + cf * 16 + r;
                #pragma unroll
                for (int jj = 0; jj < 4; ++jj) {
                    int q = row + jj;
                    O[((size_t)(q >> 5) * 96 + (col >> 3)) * 256 + (q & 31) * 8 + (col & 7)]
                        = f2bf(acc[fr][cf][jj] * scale);
                }
            }
    } else if (which == 1) {
        unsigned short* O = ws + QK_ELEMS;          // K [s/64][d/8][s%64][8]
        #pragma unroll
        for (int fr = 0; fr < 8; ++fr)
            #pragma unroll
            for (int cf = 0; cf < 2; ++cf) {
                int row = m0 + wm * 128 + fr * 16 + g * 4;
                int col = n0 + wn * 32 + cf * 16 + r;
                #pragma unroll
                for (int jj = 0; jj < 4; ++jj) {
                    int s = row + jj;
                    O[((size_t)(s >> 6) * 96 + (col >> 3)) * 512 + (s & 63) * 8 + (col & 7)]
                        = f2bf(acc[fr][cf][jj]);
                }
            }
    } else {
        unsigned short* O = ws + 2 * QK_ELEMS;      // Vf fragment-packed
        #pragma unroll
        for (int fr = 0; fr < 8; ++fr)
            #pragma unroll
            for (int cf = 0; cf < 2; ++cf) {
                int row = m0 + wm * 128 + fr * 16 + g * 4;   // = b*2048 + s
                int bb = row >> 11;
                int st = (row & 2047) >> 4;
                int et = ((n0 + wn * 32) >> 4) + cf;
                ushort4 pk;
                pk.x = f2bf(acc[fr][cf][0]); pk.y = f2bf(acc[fr][cf][1]);
                pk.z = f2bf(acc[fr][cf][2]); pk.w = f2bf(acc[fr][cf][3]);
                *(ushort4*)&O[(((size_t)bb * 128 + st) * 48 + et) * 256 + l * 4] = pk;
            }
    }
#undef STAGE_A
#undef STAGE_B
}

// ---------------- fused causal attention (R20-exact: best measured, 130.7us) -
__global__ __launch_bounds__(512, 1) void attn_kernel(
    const unsigned short* __restrict__ ws, float* __restrict__ out)
{
    __shared__ unsigned short Ks[96 * 512];     // 96 KB: [96 dg][64 s][8]
    __shared__ unsigned short Qs[96 * 256];     // 48 KB: [96 dg][32 q][8]
    __shared__ unsigned short P_lds[2048];      // [qsel][slice][16q][16k]
    __shared__ float redm[128];                 // [qsel][slice][16q] lp partials

    const int id = blockIdx.x;
    const int b = id & 7;                  // one batch per XCD
    const int a = id >> 3;                 // 0..31
    const int tid = threadIdx.x;
    const int wid = tid >> 6, lane = tid & 63;
    const int qsel = wid >> 2;             // q-tile of the pair (QK role)
    const int wv = wid & 3;                // k-slice owner (QK role)
    const int r = lane & 15, g = lane >> 4;
    const int et0 = wid * 6;               // PV role: e-eighth base (e0 = wid*96)
    const int rw = wv * 16 + r;

    const unsigned short* Qb = ws + (size_t)b * SS * DI;                // d-chunk-major
    const unsigned short* Kb = ws + QK_ELEMS + (size_t)b * SS * DI;     // d-chunk-major
    const unsigned short* Vf = ws + 2 * QK_ELEMS + (size_t)b * 128 * 48 * 256;
    float* Ob = out + (size_t)b * SS * DI;
    const char* KsB = (const char*)Ks;
    const char* QsB = (const char*)Qs;
    const int kfb = g * 1024 + rw * 16;    // per-lane K fragment base (bytes)
    const int qfb = g * 512 + (qsel * 16 + r) * 16;  // per-lane Q fragment base

#define STAGEK(KT) do { \
        const size_t sbase_ = (size_t)(KT) * 64 * DI; \
        _Pragma("unroll") \
        for (int i_ = 0; i_ < 12; ++i_) { \
            const int idx_ = wid * 12 + i_; \
            GLOAD_LDS16(Kb + sbase_ + idx_ * 512 + lane * 8, &Ks[idx_ * 512]); \
        } \
    } while (0)

#define RAWBAR() do { \
        asm volatile("s_waitcnt lgkmcnt(0)" ::: "memory"); \
        __builtin_amdgcn_sched_barrier(0); \
        __builtin_amdgcn_s_barrier(); \
        __builtin_amdgcn_sched_barrier(0); \
    } while (0)

    for (int pp = 0; pp < 2; ++pp) {
        const int jbase = pp ? (126 - 2 * a) : (2 * a);
        const int q0 = (jbase + qsel) * 16;        // own S-tile q-rows
        const int nt0 = (jbase * 16 + 79) >> 6;    // q-tile 0 activity
        const int ntmax = ((jbase + 1) * 16 + 79) >> 6;
        const int nt_own = qsel ? ntmax : nt0;

        // prologue: stage Q pair (48KB linear) + K tile 0
        {
            const size_t qsb = (size_t)jbase * 16 * DI;
            #pragma unroll
            for (int i_ = 0; i_ < 6; ++i_) {
                const int idx_ = wid * 6 + i_;
                GLOAD_LDS16(Qb + qsb + idx_ * 512 + lane * 8, &Qs[idx_ * 512]);
            }
        }
        STAGEK(0);

        f32x4 acc[2][6];
        #pragma unroll
        for (int qs = 0; qs < 2; ++qs)
            #pragma unroll
            for (int cf = 0; cf < 6; ++cf) acc[qs][cf] = (f32x4){0.f, 0.f, 0.f, 0.f};
        float lp = 0.f;

        for (int kt = 0; kt < ntmax; ++kt) {
            const int k0 = kt * 64;
            const bool act0 = kt < nt0;
            const bool act_own = kt < nt_own;
            __syncthreads();                        // A: K(kt)+Q staged (vmcnt drain)

            // V prefetch (shared by both q-tiles; consumed in PV)
            s16x4 va[4][6];
            const size_t vbase = ((size_t)(k0 >> 4) * 48 + et0) * 256 + lane * 4;
            #pragma unroll
            for (int ks = 0; ks < 4; ++ks)
                #pragma unroll
                for (int cf = 0; cf < 6; ++cf)
                    va[ks][cf] = *(const s16x4*)(Vf + vbase + (size_t)ks * 48 * 256 + cf * 256);

            if (act_own) {
                f32x4 sa = {0,0,0,0}, sb = {0,0,0,0};
                __builtin_amdgcn_s_setprio(1);
                #pragma unroll
                for (int t = 0; t < 24; t += 2) {
                    s16x8 ka  = *(const s16x8*)(KsB + kfb + t * 4096);
                    s16x8 kb2 = *(const s16x8*)(KsB + kfb + t * 4096 + 4096);
                    s16x8 qa  = *(const s16x8*)(QsB + qfb + t * 2048);
                    s16x8 qb2 = *(const s16x8*)(QsB + qfb + t * 2048 + 2048);
                    sa = __builtin_amdgcn_mfma_f32_16x16x32_bf16(ka,  qa,  sa, 0, 0, 0);
                    sb = __builtin_amdgcn_mfma_f32_16x16x32_bf16(kb2, qb2, sb, 0, 0, 0);
                }
                __builtin_amdgcn_s_setprio(0);
                f32x4 s;
                #pragma unroll
                for (int jj = 0; jj < 4; ++jj) s[jj] = sa[jj] + sb[jj];
                if (k0 + 64 > q0) {                 // boundary: causal mask
                    #pragma unroll
                    for (int jj = 0; jj < 4; ++jj)
                        if (k0 + 16 * wv + 4 * g + jj > q0 + r) s[jj] = -1e30f;
                }
                // fixed-reference softmax numerator: p = exp(s)
                s16x4 pw;
                #pragma unroll
                for (int jj = 0; jj < 4; ++jj) {
                    float p = __expf(s[jj]);
                    lp += p;
                    pw[jj] = (short)f2bf(p);
                }
                *(s16x4*)&P_lds[qsel * 1024 + wv * 256 + r * 16 + g * 4] = pw;
            }
            RAWBAR();                               // C: P ready, K consumed

            if (kt + 1 < ntmax) STAGEK(kt + 1);     // flies under PV into next A

            {
                s16x4 pa0[4], pa1[4];
                #pragma unroll
                for (int ks = 0; ks < 4; ++ks) {
                    pa0[ks] = *(const s16x4*)&P_lds[ks * 256 + r * 16 + g * 4];
                    pa1[ks] = *(const s16x4*)&P_lds[1024 + ks * 256 + r * 16 + g * 4];
                }
                __builtin_amdgcn_s_setprio(1);
                if (act0) {
                    #pragma unroll
                    for (int cf = 0; cf < 6; ++cf)
                        #pragma unroll
                        for (int ks = 0; ks < 4; ++ks)
                            acc[0][cf] = __builtin_amdgcn_mfma_f32_16x16x16bf16_1k(pa0[ks], va[ks][cf], acc[0][cf], 0, 0, 0);
                }
                #pragma unroll
                for (int cf = 0; cf < 6; ++cf)
                    #pragma unroll
                    for (int ks = 0; ks < 4; ++ks)
                        acc[1][cf] = __builtin_amdgcn_mfma_f32_16x16x16bf16_1k(pa1[ks], va[ks][cf], acc[1][cf], 0, 0, 0);
                __builtin_amdgcn_s_setprio(0);
            }
        }
        // epilogue: combine per-slice lp, normalize, store both q-tiles
        lp += __shfl_xor(lp, 16);
        lp += __shfl_xor(lp, 32);
        if (lane < 16) redm[qsel * 64 + wv * 16 + lane] = lp;
        __syncthreads();
        const float lt0 = redm[r] + redm[16 + r] + redm[32 + r] + redm[48 + r];
        const float lt1 = redm[64 + r] + redm[80 + r] + redm[96 + r] + redm[112 + r];
        const float li0 = 1.0f / lt0, li1 = 1.0f / lt1;
        float lv0[4], lv1[4];
        #pragma unroll
        for (int jj = 0; jj < 4; ++jj) {
            lv0[jj] = __shfl(li0, 4 * g + jj);
            lv1[jj] = __shfl(li1, 4 * g + jj);
        }
        #pragma unroll
        for (int cf = 0; cf < 6; ++cf)
            #pragma unroll
            for (int jj = 0; jj < 4; ++jj) {
                Ob[(size_t)(jbase * 16 + 4 * g + jj) * DI + wid * 96 + cf * 16 + r] = acc[0][cf][jj] * lv0[jj];
                Ob[(size_t)((jbase + 1) * 16 + 4 * g + jj) * DI + wid * 96 + cf * 16 + r] = acc[1][cf][jj] * lv1[jj];
            }
        __syncthreads();                            // Qs/P_lds/redm safe for next pass
    }
#undef STAGEK
#undef RAWBAR
}

extern "C" void kernel_launch(void* const* d_in, const int* in_sizes, int n_in,
                              void* d_out, int out_size, void* d_ws, size_t ws_size,
                              hipStream_t stream) {
    const float* x  = (const float*)d_in[0];
    const float* wq = (const float*)d_in[1];
    const float* wk = (const float*)d_in[2];
    const float* wv = (const float*)d_in[3];
    unsigned short* ws = (unsigned short*)d_ws;
    float* out = (float*)d_out;
    unsigned short* xb  = (unsigned short*)d_out;            // bf16(x), 25.2 MB
    unsigned short* wtb = (unsigned short*)d_out + QK_ELEMS; // bf16 W^T, 3.5 MB

    prep_kernel<<<6144 + 432, 256, 0, stream>>>(x, wq, wk, wv, xb, wtb);
    proj_kernel<<<dim3(6, 64, 3), 512, 0, stream>>>(xb, wtb, ws);
    attn_kernel<<<256, 512, 0, stream>>>(ws, out);
}